// Round 2
// baseline (2137.144 us; speedup 1.0000x reference)
//
#include <hip/hip_runtime.h>

typedef _Float16 f16;
typedef unsigned short u16;
typedef unsigned int u32;
typedef __attribute__((ext_vector_type(8))) _Float16 f16x8;
typedef __attribute__((ext_vector_type(4))) _Float16 f16x4;
typedef __attribute__((ext_vector_type(4))) float f32x4;

#define MFMA16(a, b, c) __builtin_amdgcn_mfma_f32_16x16x32_f16((a), (b), (c), 0, 0, 0)

// ---------------- weight transpose: float (R,C) -> f16 (C,R) ----------------
__global__ __launch_bounds__(256) void wt_transpose(const float* __restrict__ in,
                                                    f16* __restrict__ out, int R, int C)
{
    __shared__ float tile[32][33];
    int c0 = blockIdx.x * 32, r0 = blockIdx.y * 32;
    int tx = threadIdx.x & 31, ty = threadIdx.x >> 5;  // ty in 0..7
#pragma unroll
    for (int i = 0; i < 4; ++i)
        tile[ty + i * 8][tx] = in[(size_t)(r0 + ty + i * 8) * C + (c0 + tx)];
    __syncthreads();
#pragma unroll
    for (int i = 0; i < 4; ++i)
        out[(size_t)(c0 + ty + i * 8) * R + (r0 + tx)] = (f16)tile[tx][ty + i * 8];
}

// ---------------- LayerNorm: float in -> f16 out. wave per row (768), 4 rows/block ----------------
__global__ __launch_bounds__(256) void ln_kernel(const float* __restrict__ X,
                                                 const float* __restrict__ G,
                                                 const float* __restrict__ B,
                                                 f16* __restrict__ O)
{
    int wv = threadIdx.x >> 6, l = threadIdx.x & 63;
    size_t row = (size_t)blockIdx.x * 4 + wv;
    const float* x = X + row * 768;
    float v[12];
    float s = 0.f, s2 = 0.f;
#pragma unroll
    for (int c = 0; c < 3; ++c) {
        float4 u = *(const float4*)(x + c * 256 + l * 4);
        v[4 * c] = u.x; v[4 * c + 1] = u.y; v[4 * c + 2] = u.z; v[4 * c + 3] = u.w;
        s += (u.x + u.y) + (u.z + u.w);
        s2 += (u.x * u.x + u.y * u.y) + (u.z * u.z + u.w * u.w);
    }
#pragma unroll
    for (int off = 32; off >= 1; off >>= 1) {
        s += __shfl_xor(s, off);
        s2 += __shfl_xor(s2, off);
    }
    float mu = s * (1.f / 768.f);
    float var = s2 * (1.f / 768.f) - mu * mu;
    float rs = rsqrtf(var + 1e-5f);
    f16* o = O + row * 768;
#pragma unroll
    for (int c = 0; c < 3; ++c) {
        float4 ug = *(const float4*)(G + c * 256 + l * 4);
        float4 ub = *(const float4*)(B + c * 256 + l * 4);
        f16x4 ov;
        ov.x = (f16)((v[4 * c]     - mu) * rs * ug.x + ub.x);
        ov.y = (f16)((v[4 * c + 1] - mu) * rs * ug.y + ub.y);
        ov.z = (f16)((v[4 * c + 2] - mu) * rs * ug.z + ub.z);
        ov.w = (f16)((v[4 * c + 3] - mu) * rs * ug.w + ub.w);
        *(f16x4*)(o + c * 256 + l * 4) = ov;
    }
}

// ---------------- GEMM: Out(f32) = A(f16) @ B + bias(f32) + Res(f32), M=50176 K=768 N=768 ----------------
// A row-major (M,768) f16; BT = B transposed, row-major (768,768) f16.
// 128x128 tile, 4 waves, each wave 64x64 via 4x4 of 16x16x32 MFMA.
__global__ __launch_bounds__(256) void gemm_bias_res(const f16* __restrict__ A,
                                                     const f16* __restrict__ BT,
                                                     const float* __restrict__ bias,
                                                     const float* __restrict__ Res,
                                                     float* __restrict__ Out)
{
    __shared__ f16 As[128 * 40];  // 80B row stride -> 2-way (free) bank aliasing
    __shared__ f16 Bs[128 * 40];
    const int n0 = blockIdx.x * 128, m0 = blockIdx.y * 128;
    const int t = threadIdx.x;
    const int wv = t >> 6, l = t & 63, lm = l & 15, quad = l >> 4;
    const int srow = t >> 1, shalf = t & 1;
    const f16* gA = A + (size_t)(m0 + srow) * 768 + shalf * 16;
    const f16* gB = BT + (size_t)(n0 + srow) * 768 + shalf * 16;
    f16* sA = As + srow * 40 + shalf * 16;
    f16* sB = Bs + srow * 40 + shalf * 16;
    const int wm = (wv >> 1) * 64, wn = (wv & 1) * 64;
    f32x4 acc[4][4];
    f32x4 zero = {0.f, 0.f, 0.f, 0.f};
#pragma unroll
    for (int i = 0; i < 4; ++i)
#pragma unroll
        for (int j = 0; j < 4; ++j) acc[i][j] = zero;

    for (int k0 = 0; k0 < 768; k0 += 32) {
        uint4 a0 = *(const uint4*)(gA + k0);
        uint4 a1 = *(const uint4*)(gA + k0 + 8);
        uint4 b0 = *(const uint4*)(gB + k0);
        uint4 b1 = *(const uint4*)(gB + k0 + 8);
        *(uint4*)sA = a0; *(uint4*)(sA + 8) = a1;
        *(uint4*)sB = b0; *(uint4*)(sB + 8) = b1;
        __syncthreads();
        f16x8 af[4], bfr[4];
#pragma unroll
        for (int mt = 0; mt < 4; ++mt)
            af[mt] = *(const f16x8*)(As + (wm + mt * 16 + lm) * 40 + quad * 8);
#pragma unroll
        for (int nt = 0; nt < 4; ++nt)
            bfr[nt] = *(const f16x8*)(Bs + (wn + nt * 16 + lm) * 40 + quad * 8);
#pragma unroll
        for (int mt = 0; mt < 4; ++mt)
#pragma unroll
            for (int nt = 0; nt < 4; ++nt)
                acc[mt][nt] = MFMA16(af[mt], bfr[nt], acc[mt][nt]);
        __syncthreads();
    }
#pragma unroll
    for (int nt = 0; nt < 4; ++nt) {
        const int colg = n0 + wn + nt * 16 + lm;
        const float bv = bias[colg];
#pragma unroll
        for (int mt = 0; mt < 4; ++mt) {
#pragma unroll
            for (int reg = 0; reg < 4; ++reg) {
                const size_t rowg = (size_t)(m0 + wm + mt * 16 + quad * 4 + reg);
                const size_t idx = rowg * 768 + colg;
                Out[idx] = acc[mt][nt][reg] + bv + Res[idx];
            }
        }
    }
}

// ---------------- fused window attention: one block per (window, head) ----------------
// qkv = H@Wqkv[head]+b, S = QK^T/8, softmax (cols<49), O = PV -> Out (f16).
// roff: 0 (W-MSA) or 53 (SW-MSA: read/write h at (r-3 mod 56, c-3 mod 56)).
// Mask (1-eq)*1e-9 is numerically a no-op in fp32 -> skipped.
__global__ __launch_bounds__(256) void attn_kernel(const f16* __restrict__ H,
                                                   const f16* __restrict__ WqkvT,  // (2304,768)
                                                   const float* __restrict__ Bqkv, // (2304)
                                                   f16* __restrict__ Out,
                                                   int roff)
{
    __shared__ __align__(16) char smem[20480];   // phase1: hT(64x40)+wT(192x40) f16; phase3+: S(64x68 f32)
    f16* hT = (f16*)smem;
    f16* wT = (f16*)(smem + 5120);
    float* S = (float*)smem;
    __shared__ f16 Qs[64 * 72];  // Q, later reused as P
    __shared__ f16 Ks[64 * 72];
    __shared__ f16 Vs[64 * 72];  // stored transposed: Vs[d][token]
    __shared__ int rowmap[64];

    const int blk = blockIdx.x;
    const int head = blk % 12;
    const int widx = blk / 12;
    const int bb = widx >> 6;
    const int w = widx & 63;
    const int wy = w >> 3, wx = w & 7;

    const int t = threadIdx.x;
    const int wv = t >> 6, l = t & 63, lm = l & 15, quad = l >> 4;

    if (t < 64) {
        int rm = -1;
        if (t < 49) {
            int ty = t / 7, tx = t % 7;
            int rr = (wy * 7 + ty + roff) % 56;
            int cc = (wx * 7 + tx + roff) % 56;
            rm = bb * 3136 + rr * 56 + cc;
        }
        rowmap[t] = rm;
    }
    __syncthreads();

    // ---- phase 1: qkv GEMM. wave wv owns qkv-cols [wv*48, wv*48+48), all 64 token rows.
    const int hrow = t >> 2, hseg = t & 3;
    const int gr = rowmap[hrow];
    const f16* gH = H + (size_t)(gr < 0 ? 0 : gr) * 768 + hseg * 8;
    const f16* gW = WqkvT + (size_t)(head * 64 + hrow) * 768 + hseg * 8;

    f32x4 zero = {0.f, 0.f, 0.f, 0.f};
    f32x4 acc[4][3];
#pragma unroll
    for (int i = 0; i < 4; ++i)
#pragma unroll
        for (int j = 0; j < 3; ++j) acc[i][j] = zero;

    for (int k0 = 0; k0 < 768; k0 += 32) {
        uint4 hv;
        if (gr >= 0) hv = *(const uint4*)(gH + k0);
        else { hv.x = 0u; hv.y = 0u; hv.z = 0u; hv.w = 0u; }
        *(uint4*)(hT + hrow * 40 + hseg * 8) = hv;
#pragma unroll
        for (int p = 0; p < 3; ++p) {
            uint4 wvv = *(const uint4*)(gW + (size_t)p * 768 * 768 + k0);
            *(uint4*)(wT + (p * 64 + hrow) * 40 + hseg * 8) = wvv;
        }
        __syncthreads();
        f16x8 af[4];
#pragma unroll
        for (int mt = 0; mt < 4; ++mt)
            af[mt] = *(const f16x8*)(hT + (mt * 16 + lm) * 40 + quad * 8);
#pragma unroll
        for (int j = 0; j < 3; ++j) {
            f16x8 bw = *(const f16x8*)(wT + ((wv * 3 + j) * 16 + lm) * 40 + quad * 8);
#pragma unroll
            for (int mt = 0; mt < 4; ++mt)
                acc[mt][j] = MFMA16(af[mt], bw, acc[mt][j]);
        }
        __syncthreads();
    }

    // ---- phase 2: accs -> Q/K/V LDS (f16, +bias). V stored transposed.
#pragma unroll
    for (int j = 0; j < 3; ++j) {
        int col = wv * 48 + j * 16 + lm;   // 0..191
        int seg = col >> 6, cc = col & 63; // seg uniform per (wv,j)
        float bv = Bqkv[seg * 768 + head * 64 + cc];
#pragma unroll
        for (int mt = 0; mt < 4; ++mt)
#pragma unroll
            for (int reg = 0; reg < 4; ++reg) {
                int row = mt * 16 + quad * 4 + reg;
                f16 val = (f16)(acc[mt][j][reg] + bv);
                if (seg == 0)      Qs[row * 72 + cc] = val;
                else if (seg == 1) Ks[row * 72 + cc] = val;
                else               Vs[cc * 72 + row] = val;
            }
    }
    __syncthreads();

    // ---- phase 3: S = Q@K^T * 0.125. wave wv owns token rows wv*16..+16.
    f32x4 sacc[4];
#pragma unroll
    for (int i = 0; i < 4; ++i) sacc[i] = zero;
#pragma unroll
    for (int kk = 0; kk < 2; ++kk) {
        f16x8 aq = *(const f16x8*)(Qs + (wv * 16 + lm) * 72 + kk * 32 + quad * 8);
#pragma unroll
        for (int nt = 0; nt < 4; ++nt) {
            f16x8 bk = *(const f16x8*)(Ks + (nt * 16 + lm) * 72 + kk * 32 + quad * 8);
            sacc[nt] = MFMA16(aq, bk, sacc[nt]);
        }
    }
#pragma unroll
    for (int nt = 0; nt < 4; ++nt)
#pragma unroll
        for (int reg = 0; reg < 4; ++reg)
            S[(wv * 16 + quad * 4 + reg) * 68 + nt * 16 + lm] = sacc[nt][reg] * 0.125f;
    __syncthreads();

    // ---- phase 4: softmax rows (cols 0..48 only); P -> Qs (reuse), pad cols zeroed.
    if (t < 64) {
        float mx = -1e30f;
        for (int j = 0; j < 49; ++j) mx = fmaxf(mx, S[t * 68 + j]);
        float sum = 0.f;
        for (int j = 0; j < 49; ++j) {
            float e = __expf(S[t * 68 + j] - mx);
            sum += e;
            S[t * 68 + j] = e;
        }
        float inv = 1.f / sum;
        for (int j = 0; j < 49; ++j) Qs[t * 72 + j] = (f16)(S[t * 68 + j] * inv);
        for (int j = 49; j < 64; ++j) Qs[t * 72 + j] = (f16)0.f;
    }
    __syncthreads();

    // ---- phase 5: O = P@V
    f32x4 oacc[4];
#pragma unroll
    for (int i = 0; i < 4; ++i) oacc[i] = zero;
#pragma unroll
    for (int kk = 0; kk < 2; ++kk) {
        f16x8 ap = *(const f16x8*)(Qs + (wv * 16 + lm) * 72 + kk * 32 + quad * 8);
#pragma unroll
        for (int nt = 0; nt < 4; ++nt) {
            f16x8 bv8 = *(const f16x8*)(Vs + (nt * 16 + lm) * 72 + kk * 32 + quad * 8);
            oacc[nt] = MFMA16(ap, bv8, oacc[nt]);
        }
    }
    // ---- phase 6: write out (window-merge via same rowmap)
#pragma unroll
    for (int nt = 0; nt < 4; ++nt)
#pragma unroll
        for (int reg = 0; reg < 4; ++reg) {
            int tok = wv * 16 + quad * 4 + reg;
            if (tok < 49) {
                size_t grow = (size_t)rowmap[tok];
                Out[grow * 768 + head * 64 + nt * 16 + lm] = (f16)oacc[nt][reg];
            }
        }
}

extern "C" void kernel_launch(void* const* d_in, const int* in_sizes, int n_in,
                              void* d_out, int out_size, void* d_ws, size_t ws_size,
                              hipStream_t stream)
{
    (void)in_sizes; (void)n_in; (void)out_size; (void)ws_size;
    const float* x     = (const float*)d_in[0];
    const float* g1    = (const float*)d_in[1];
    const float* b1    = (const float*)d_in[2];
    const float* Wqkv1 = (const float*)d_in[3];
    const float* bqkv1 = (const float*)d_in[4];
    const float* Wo1   = (const float*)d_in[5];
    const float* bo1   = (const float*)d_in[6];
    const float* g2    = (const float*)d_in[7];
    const float* b2    = (const float*)d_in[8];
    const float* g3    = (const float*)d_in[9];
    const float* b3    = (const float*)d_in[10];
    const float* Wqkv2 = (const float*)d_in[11];
    const float* bqkv2 = (const float*)d_in[12];
    const float* Wo2   = (const float*)d_in[13];
    const float* bo2   = (const float*)d_in[14];
    const float* g4    = (const float*)d_in[15];
    const float* b4    = (const float*)d_in[16];
    const float* Wl    = (const float*)d_in[17];
    const float* bl    = (const float*)d_in[18];
    float* out = (float*)d_out;

    char* ws = (char*)d_ws;
    f16* hbuf  = (f16*)(ws);               // 50176*768 f16 = 77,070,336 B
    f16* abuf  = (f16*)(ws + 77070336);    // 77,070,336 B
    f16* qkvT1 = (f16*)(ws + 154140672);   // 2304x768 = 3,538,944 B
    f16* woT1  = (f16*)(ws + 157679616);   // 768x768  = 1,179,648 B
    f16* qkvT2 = (f16*)(ws + 158859264);
    f16* woT2  = (f16*)(ws + 162398208);
    f16* wlT   = (f16*)(ws + 163577856);   // ends at 164,757,504 B

    dim3 blk(256);
    // per-launch weight transposes -> (N,K) row-major f16
    wt_transpose<<<dim3(72, 24), blk, 0, stream>>>(Wqkv1, qkvT1, 768, 2304);
    wt_transpose<<<dim3(24, 24), blk, 0, stream>>>(Wo1,   woT1,  768, 768);
    wt_transpose<<<dim3(72, 24), blk, 0, stream>>>(Wqkv2, qkvT2, 768, 2304);
    wt_transpose<<<dim3(24, 24), blk, 0, stream>>>(Wo2,   woT2,  768, 768);
    wt_transpose<<<dim3(24, 24), blk, 0, stream>>>(Wl,    wlT,   768, 768);

    // --- W-MSA ---
    ln_kernel<<<12544, blk, 0, stream>>>(x, g1, b1, hbuf);
    attn_kernel<<<12288, blk, 0, stream>>>(hbuf, qkvT1, bqkv1, abuf, 0);
    gemm_bias_res<<<dim3(6, 392), blk, 0, stream>>>(abuf, woT1, bo1, x, out);      // x1 = x + proj
    // --- MLP ---
    ln_kernel<<<12544, blk, 0, stream>>>(out, g2, b2, hbuf);
    gemm_bias_res<<<dim3(6, 392), blk, 0, stream>>>(hbuf, wlT, bl, out, out);      // x2
    // --- SW-MSA (roff=53 == -3 mod 56) ---
    ln_kernel<<<12544, blk, 0, stream>>>(out, g3, b3, hbuf);
    attn_kernel<<<12288, blk, 0, stream>>>(hbuf, qkvT2, bqkv2, abuf, 53);
    gemm_bias_res<<<dim3(6, 392), blk, 0, stream>>>(abuf, woT2, bo2, out, out);    // x3
    // --- MLP ---
    ln_kernel<<<12544, blk, 0, stream>>>(out, g4, b4, hbuf);
    gemm_bias_res<<<dim3(6, 392), blk, 0, stream>>>(hbuf, wlT, bl, out, out);      // final
}

// Round 3
// 1690.298 us; speedup vs baseline: 1.2644x; 1.2644x over previous
//
#include <hip/hip_runtime.h>

typedef _Float16 f16;
typedef unsigned int u32;
typedef __attribute__((ext_vector_type(8))) _Float16 f16x8;
typedef __attribute__((ext_vector_type(4))) _Float16 f16x4;
typedef __attribute__((ext_vector_type(4))) float f32x4;

#define MFMA16(a, b, c) __builtin_amdgcn_mfma_f32_16x16x32_f16((a), (b), (c), 0, 0, 0)

// async global->LDS, 16B per lane. lds base must be wave-uniform; HW writes base + lane*16.
static __device__ __forceinline__ void async16(f16* ldsBase, const f16* g, int lane)
{
#if __has_builtin(__builtin_amdgcn_global_load_lds)
    __builtin_amdgcn_global_load_lds((__attribute__((address_space(1))) void*)(g),
                                     (__attribute__((address_space(3))) void*)(ldsBase),
                                     16, 0, 0);
#else
    *(uint4*)(ldsBase + lane * 8) = *(const uint4*)g;
#endif
}

// ---------------- weight transpose: float (R,C) -> f16 (C,R) ----------------
__global__ __launch_bounds__(256) void wt_transpose(const float* __restrict__ in,
                                                    f16* __restrict__ out, int R, int C)
{
    __shared__ float tile[32][33];
    int c0 = blockIdx.x * 32, r0 = blockIdx.y * 32;
    int tx = threadIdx.x & 31, ty = threadIdx.x >> 5;
#pragma unroll
    for (int i = 0; i < 4; ++i)
        tile[ty + i * 8][tx] = in[(size_t)(r0 + ty + i * 8) * C + (c0 + tx)];
    __syncthreads();
#pragma unroll
    for (int i = 0; i < 4; ++i)
        out[(size_t)(c0 + ty + i * 8) * R + (r0 + tx)] = (f16)tile[tx][ty + i * 8];
}

// ---------------- LayerNorm: float in -> f16 out. wave per row (768) ----------------
__global__ __launch_bounds__(256) void ln_kernel(const float* __restrict__ X,
                                                 const float* __restrict__ G,
                                                 const float* __restrict__ B,
                                                 f16* __restrict__ O)
{
    int wv = threadIdx.x >> 6, l = threadIdx.x & 63;
    size_t row = (size_t)blockIdx.x * 4 + wv;
    const float* x = X + row * 768;
    float v[12];
    float s = 0.f, s2 = 0.f;
#pragma unroll
    for (int c = 0; c < 3; ++c) {
        float4 u = *(const float4*)(x + c * 256 + l * 4);
        v[4 * c] = u.x; v[4 * c + 1] = u.y; v[4 * c + 2] = u.z; v[4 * c + 3] = u.w;
        s += (u.x + u.y) + (u.z + u.w);
        s2 += (u.x * u.x + u.y * u.y) + (u.z * u.z + u.w * u.w);
    }
#pragma unroll
    for (int off = 32; off >= 1; off >>= 1) {
        s += __shfl_xor(s, off);
        s2 += __shfl_xor(s2, off);
    }
    float mu = s * (1.f / 768.f);
    float var = s2 * (1.f / 768.f) - mu * mu;
    float rs = rsqrtf(var + 1e-5f);
    f16* o = O + row * 768;
#pragma unroll
    for (int c = 0; c < 3; ++c) {
        float4 ug = *(const float4*)(G + c * 256 + l * 4);
        float4 ub = *(const float4*)(B + c * 256 + l * 4);
        f16x4 ov;
        ov.x = (f16)((v[4 * c]     - mu) * rs * ug.x + ub.x);
        ov.y = (f16)((v[4 * c + 1] - mu) * rs * ug.y + ub.y);
        ov.z = (f16)((v[4 * c + 2] - mu) * rs * ug.z + ub.z);
        ov.w = (f16)((v[4 * c + 3] - mu) * rs * ug.w + ub.w);
        *(f16x4*)(o + c * 256 + l * 4) = ov;
    }
}

// ---------------- GEMM (m97 structure): C = A(f16,Mx768) @ BT(f16,Nx768)^T + bias ----------------
// Out16 != null: Out16 = f16(acc+bias), no residual (qkv path, row stride N).
// else:          Out32 = acc + bias + Res (fp32, N=768 proj/MLP path).
// 128x128 tile, BK=32, unpadded LDS (required by global_load_lds), 4 waves x (64x64).
__global__ __launch_bounds__(256) void gemm_kernel(const f16* __restrict__ A,
                                                   const f16* __restrict__ BT,
                                                   const float* __restrict__ bias,
                                                   const float* __restrict__ Res,
                                                   float* __restrict__ Out32,
                                                   f16* __restrict__ Out16,
                                                   int N)
{
    __shared__ __align__(16) f16 As[128 * 32];
    __shared__ __align__(16) f16 Bs[128 * 32];
    const int n0 = blockIdx.x * 128, m0 = blockIdx.y * 128;
    const int t = threadIdx.x, wv = t >> 6, l = t & 63, lm = l & 15, quad = l >> 4;
    // staging: lane l of wave wv covers LDS bytes wv*1024 + l*16 (rows wv*16 + l/4)
    const int rt = wv * 16 + (l >> 2);
    const int cs = (l & 3) * 8;
    const f16* gA = A + (size_t)(m0 + rt) * 768 + cs;
    const f16* gB = BT + (size_t)(n0 + rt) * 768 + cs;
    f16* sA0 = As + wv * 16 * 32;          // wave-uniform bases
    f16* sA1 = As + (64 + wv * 16) * 32;
    f16* sB0 = Bs + wv * 16 * 32;
    f16* sB1 = Bs + (64 + wv * 16) * 32;
    const int wm = (wv >> 1) * 64, wn = (wv & 1) * 64;
    f32x4 acc[4][4];
    f32x4 zero = {0.f, 0.f, 0.f, 0.f};
#pragma unroll
    for (int i = 0; i < 4; ++i)
#pragma unroll
        for (int j = 0; j < 4; ++j) acc[i][j] = zero;

    for (int k0 = 0; k0 < 768; k0 += 32) {
        async16(sA0, gA + k0, l);
        async16(sA1, gA + 64 * 768 + k0, l);
        async16(sB0, gB + k0, l);
        async16(sB1, gB + 64 * 768 + k0, l);
        __syncthreads();
        f16x8 af[4], bf[4];
#pragma unroll
        for (int mt = 0; mt < 4; ++mt)
            af[mt] = *(const f16x8*)(As + (wm + mt * 16 + lm) * 32 + quad * 8);
#pragma unroll
        for (int nt = 0; nt < 4; ++nt)
            bf[nt] = *(const f16x8*)(Bs + (wn + nt * 16 + lm) * 32 + quad * 8);
#pragma unroll
        for (int mt = 0; mt < 4; ++mt)
#pragma unroll
            for (int nt = 0; nt < 4; ++nt)
                acc[mt][nt] = MFMA16(af[mt], bf[nt], acc[mt][nt]);
        __syncthreads();
    }

    if (Out16) {
#pragma unroll
        for (int nt = 0; nt < 4; ++nt) {
            const int colg = n0 + wn + nt * 16 + lm;
            const float bv = bias[colg];
#pragma unroll
            for (int mt = 0; mt < 4; ++mt)
#pragma unroll
                for (int reg = 0; reg < 4; ++reg) {
                    const size_t rowg = (size_t)(m0 + wm + mt * 16 + quad * 4 + reg);
                    Out16[rowg * N + colg] = (f16)(acc[mt][nt][reg] + bv);
                }
        }
    } else {
#pragma unroll
        for (int nt = 0; nt < 4; ++nt) {
            const int colg = n0 + wn + nt * 16 + lm;
            const float bv = bias[colg];
#pragma unroll
            for (int mt = 0; mt < 4; ++mt)
#pragma unroll
                for (int reg = 0; reg < 4; ++reg) {
                    const size_t rowg = (size_t)(m0 + wm + mt * 16 + quad * 4 + reg);
                    const size_t idx = rowg * 768 + colg;
                    Out32[idx] = acc[mt][nt][reg] + bv + Res[idx];
                }
        }
    }
}

// ---------------- light attention: one block per (window, head) within a 4-image chunk ----------
// QKV: (12544, 2304) f16 chunk (Q|K|V). Hc: hbuf chunk base (output, token order, 768 wide).
// S/softmax kept in registers; P round-trips through LDS (reuses Ks) for the A-fragment layout.
__global__ __launch_bounds__(256) void attn2_kernel(const f16* __restrict__ QKV,
                                                    f16* __restrict__ Hc,
                                                    int roff)
{
    __shared__ __align__(16) f16 Qs[64 * 72];
    __shared__ __align__(16) f16 Ks[64 * 72];   // reused as P after softmax
    __shared__ __align__(16) f16 Vs[64 * 72];   // transposed: Vs[d][token]
    __shared__ int rowmap[64];

    const int head = blockIdx.x % 12;
    const int widx = blockIdx.x / 12;    // 0..255 (4 images x 64 windows)
    const int bbL = widx >> 6;
    const int w = widx & 63, wy = w >> 3, wx = w & 7;
    const int t = threadIdx.x, wvid = t >> 6, l = t & 63, lm = l & 15, quad = l >> 4;

    if (t < 64) {
        int rm = -1;
        if (t < 49) {
            int ty = t / 7, tx = t % 7;
            int rr = (wy * 7 + ty + roff) % 56;
            int cc = (wx * 7 + tx + roff) % 56;
            rm = bbL * 3136 + rr * 56 + cc;
        }
        rowmap[t] = rm;
    }
    __syncthreads();

    // load Q,K,V (49 real rows; pad rows zero). thread t: row t>>2, 16-col segment t&3.
    const int row = t >> 2, s4 = t & 3;
    const int gr = rowmap[row];
    f16x8 q0 = {}, q1 = {}, k0 = {}, k1 = {}, v0 = {}, v1 = {};
    if (gr >= 0) {
        const f16* p = QKV + (size_t)gr * 2304 + head * 64 + s4 * 16;
        q0 = *(const f16x8*)(p);        q1 = *(const f16x8*)(p + 8);
        k0 = *(const f16x8*)(p + 768);  k1 = *(const f16x8*)(p + 776);
        v0 = *(const f16x8*)(p + 1536); v1 = *(const f16x8*)(p + 1544);
    }
    *(f16x8*)(Qs + row * 72 + s4 * 16) = q0;
    *(f16x8*)(Qs + row * 72 + s4 * 16 + 8) = q1;
    *(f16x8*)(Ks + row * 72 + s4 * 16) = k0;
    *(f16x8*)(Ks + row * 72 + s4 * 16 + 8) = k1;
#pragma unroll
    for (int j = 0; j < 8; ++j) {
        Vs[(s4 * 16 + j) * 72 + row] = v0[j];
        Vs[(s4 * 16 + 8 + j) * 72 + row] = v1[j];
    }
    __syncthreads();

    // S = Q@K^T. wave wvid owns rows wvid*16..+15; lane holds rows quad*4+reg, cols nt*16+lm.
    f32x4 zero = {0.f, 0.f, 0.f, 0.f};
    f32x4 sacc[4] = {zero, zero, zero, zero};
#pragma unroll
    for (int kk = 0; kk < 2; ++kk) {
        f16x8 aq = *(const f16x8*)(Qs + (wvid * 16 + lm) * 72 + kk * 32 + quad * 8);
#pragma unroll
        for (int nt = 0; nt < 4; ++nt) {
            f16x8 bk = *(const f16x8*)(Ks + (nt * 16 + lm) * 72 + kk * 32 + quad * 8);
            sacc[nt] = MFMA16(aq, bk, sacc[nt]);
        }
    }

    // in-register softmax over cols (valid cols < 49); reduce over lm bits 1,2,4,8.
    float mx[4] = {-1e30f, -1e30f, -1e30f, -1e30f};
#pragma unroll
    for (int nt = 0; nt < 4; ++nt) {
        bool valid = (nt * 16 + lm) < 49;
#pragma unroll
        for (int reg = 0; reg < 4; ++reg) {
            float v = sacc[nt][reg] * 0.125f;
            if (valid) mx[reg] = fmaxf(mx[reg], v);
        }
    }
#pragma unroll
    for (int off = 1; off < 16; off <<= 1)
#pragma unroll
        for (int reg = 0; reg < 4; ++reg) mx[reg] = fmaxf(mx[reg], __shfl_xor(mx[reg], off));
    float sum[4] = {0.f, 0.f, 0.f, 0.f};
    float pr[4][4];
#pragma unroll
    for (int nt = 0; nt < 4; ++nt) {
        bool valid = (nt * 16 + lm) < 49;
#pragma unroll
        for (int reg = 0; reg < 4; ++reg) {
            float e = valid ? __expf(sacc[nt][reg] * 0.125f - mx[reg]) : 0.f;
            pr[nt][reg] = e;
            sum[reg] += e;
        }
    }
#pragma unroll
    for (int off = 1; off < 16; off <<= 1)
#pragma unroll
        for (int reg = 0; reg < 4; ++reg) sum[reg] += __shfl_xor(sum[reg], off);
    float inv[4];
#pragma unroll
    for (int reg = 0; reg < 4; ++reg) inv[reg] = 1.f / sum[reg];

    __syncthreads();  // all K reads done before P overwrites Ks
#pragma unroll
    for (int nt = 0; nt < 4; ++nt)
#pragma unroll
        for (int reg = 0; reg < 4; ++reg)
            Ks[(wvid * 16 + quad * 4 + reg) * 72 + nt * 16 + lm] = (f16)(pr[nt][reg] * inv[reg]);
    __syncthreads();

    // O = P@V
    f32x4 oacc[4] = {zero, zero, zero, zero};
#pragma unroll
    for (int kk = 0; kk < 2; ++kk) {
        f16x8 ap = *(const f16x8*)(Ks + (wvid * 16 + lm) * 72 + kk * 32 + quad * 8);
#pragma unroll
        for (int nt = 0; nt < 4; ++nt) {
            f16x8 bv8 = *(const f16x8*)(Vs + (nt * 16 + lm) * 72 + kk * 32 + quad * 8);
            oacc[nt] = MFMA16(ap, bv8, oacc[nt]);
        }
    }
#pragma unroll
    for (int nt = 0; nt < 4; ++nt)
#pragma unroll
        for (int reg = 0; reg < 4; ++reg) {
            int tok = wvid * 16 + quad * 4 + reg;
            if (tok < 49) {
                size_t grow = (size_t)rowmap[tok];
                Hc[grow * 768 + head * 64 + nt * 16 + lm] = (f16)oacc[nt][reg];
            }
        }
}

extern "C" void kernel_launch(void* const* d_in, const int* in_sizes, int n_in,
                              void* d_out, int out_size, void* d_ws, size_t ws_size,
                              hipStream_t stream)
{
    (void)in_sizes; (void)n_in; (void)out_size; (void)ws_size;
    const float* x     = (const float*)d_in[0];
    const float* g1    = (const float*)d_in[1];
    const float* b1    = (const float*)d_in[2];
    const float* Wqkv1 = (const float*)d_in[3];
    const float* bqkv1 = (const float*)d_in[4];
    const float* Wo1   = (const float*)d_in[5];
    const float* bo1   = (const float*)d_in[6];
    const float* g2    = (const float*)d_in[7];
    const float* b2    = (const float*)d_in[8];
    const float* g3    = (const float*)d_in[9];
    const float* b3    = (const float*)d_in[10];
    const float* Wqkv2 = (const float*)d_in[11];
    const float* bqkv2 = (const float*)d_in[12];
    const float* Wo2   = (const float*)d_in[13];
    const float* bo2   = (const float*)d_in[14];
    const float* g4    = (const float*)d_in[15];
    const float* b4    = (const float*)d_in[16];
    const float* Wl    = (const float*)d_in[17];
    const float* bl    = (const float*)d_in[18];
    float* out = (float*)d_out;

    char* ws = (char*)d_ws;
    f16* hbuf  = (f16*)(ws);                 // 50176*768 f16 = 77,070,336 B
    f16* qkvc  = (f16*)(ws + 77070336);      // 12544*2304 f16 = 57,802,752 B (chunk)
    f16* qkvT1 = (f16*)(ws + 134873088);     // 3,538,944 B
    f16* woT1  = (f16*)(ws + 138412032);     // 1,179,648 B
    f16* qkvT2 = (f16*)(ws + 139591680);
    f16* woT2  = (f16*)(ws + 143130624);
    f16* wlT   = (f16*)(ws + 144310272);     // ends 145,489,920 B (< proven 164.7 MB)

    dim3 blk(256);
    wt_transpose<<<dim3(72, 24), blk, 0, stream>>>(Wqkv1, qkvT1, 768, 2304);
    wt_transpose<<<dim3(24, 24), blk, 0, stream>>>(Wo1,   woT1,  768, 768);
    wt_transpose<<<dim3(72, 24), blk, 0, stream>>>(Wqkv2, qkvT2, 768, 2304);
    wt_transpose<<<dim3(24, 24), blk, 0, stream>>>(Wo2,   woT2,  768, 768);
    wt_transpose<<<dim3(24, 24), blk, 0, stream>>>(Wl,    wlT,   768, 768);

    // --- W-MSA ---
    ln_kernel<<<12544, blk, 0, stream>>>(x, g1, b1, hbuf);
    for (int c = 0; c < 4; ++c) {
        f16* hc = hbuf + (size_t)c * 12544 * 768;
        gemm_kernel<<<dim3(18, 98), blk, 0, stream>>>(hc, qkvT1, bqkv1, nullptr, nullptr, qkvc, 2304);
        attn2_kernel<<<3072, blk, 0, stream>>>(qkvc, hc, 0);   // writes attn-out over its own h rows
    }
    gemm_kernel<<<dim3(6, 392), blk, 0, stream>>>(hbuf, woT1, bo1, x, out, nullptr, 768);
    // --- MLP ---
    ln_kernel<<<12544, blk, 0, stream>>>(out, g2, b2, hbuf);
    gemm_kernel<<<dim3(6, 392), blk, 0, stream>>>(hbuf, wlT, bl, out, out, nullptr, 768);
    // --- SW-MSA (roff=53 == -3 mod 56) ---
    ln_kernel<<<12544, blk, 0, stream>>>(out, g3, b3, hbuf);
    for (int c = 0; c < 4; ++c) {
        f16* hc = hbuf + (size_t)c * 12544 * 768;
        gemm_kernel<<<dim3(18, 98), blk, 0, stream>>>(hc, qkvT2, bqkv2, nullptr, nullptr, qkvc, 2304);
        attn2_kernel<<<3072, blk, 0, stream>>>(qkvc, hc, 53);
    }
    gemm_kernel<<<dim3(6, 392), blk, 0, stream>>>(hbuf, woT2, bo2, out, out, nullptr, 768);
    // --- MLP ---
    ln_kernel<<<12544, blk, 0, stream>>>(out, g4, b4, hbuf);
    gemm_kernel<<<dim3(6, 392), blk, 0, stream>>>(hbuf, wlT, bl, out, out, nullptr, 768);
}